// Round 3
// baseline (631.522 us; speedup 1.0000x reference)
//
#include <hip/hip_runtime.h>
#include <hip/hip_bf16.h>
#include <math.h>

typedef unsigned short u16;
typedef __attribute__((ext_vector_type(8))) short bf16x8;
typedef __attribute__((ext_vector_type(8))) unsigned short us8;
typedef __attribute__((ext_vector_type(4))) float f32x4;

static __device__ __forceinline__ u16 f2bf(float f) {
  __hip_bfloat16 h = __float2bfloat16(f);
  return *reinterpret_cast<u16*>(&h);
}

// ---------------------------------------------------------------------------
// K0: x fp32 -> bf16 (288x1024)
// ---------------------------------------------------------------------------
__global__ __launch_bounds__(256) void conv_x(const float* __restrict__ x,
                                              u16* __restrict__ xb) {
  int idx = (blockIdx.x * 256 + threadIdx.x) * 4;
  float4 v = *(const float4*)(x + idx);
  ushort4 o;
  o.x = f2bf(v.x); o.y = f2bf(v.y); o.z = f2bf(v.z); o.w = f2bf(v.w);
  *(ushort4*)(xb + idx) = o;
}

// ---------------------------------------------------------------------------
// K0b: W_proj [1024][150] fp32 -> WT4 [p][160][1024] bf16, pads (j>=150) zero
// ---------------------------------------------------------------------------
__global__ __launch_bounds__(256) void trans_wp(
    const float* __restrict__ W0, const float* __restrict__ W1,
    const float* __restrict__ W2, const float* __restrict__ W3,
    u16* __restrict__ WT4) {
  __shared__ float lds[64 * 151];
  int kt = blockIdx.x, p = blockIdx.y;
  const float* W = (p == 0) ? W0 : (p == 1) ? W1 : (p == 2) ? W2 : W3;
  for (int t = threadIdx.x; t < 64 * 150; t += 256) {
    int k = t / 150, j = t - k * 150;
    lds[k * 151 + j] = W[(size_t)(kt * 64 + k) * 150 + j];
  }
  __syncthreads();
  u16* dst = WT4 + (size_t)p * 160 * 1024 + kt * 64;
  for (int t = threadIdx.x; t < 160 * 64; t += 256) {
    int j = t >> 6, kk = t & 63;
    float v = (j < 150) ? lds[kk * 151 + j] : 0.f;
    dst[(size_t)j * 1024 + kk] = f2bf(v);
  }
}

// ---------------------------------------------------------------------------
// transpose W_tri [600 oi][150 k][150 j] fp32 -> WtT [tri][600][160 j][160 k]
// bf16. grid (600, 2 jhalf, 2 tri). LDS 49.2 KB -> 3 blocks/CU.
// ---------------------------------------------------------------------------
__global__ __launch_bounds__(256) void transw2(const float* __restrict__ Wa,
                                               const float* __restrict__ Wb,
                                               u16* __restrict__ WtT) {
  __shared__ float lds[150 * 82];
  int oi = blockIdx.x, jh = blockIdx.y, tri = blockIdx.z;
  const float* W = tri ? Wb : Wa;
  const float* src = W + (size_t)oi * 22500 + jh * 80;
  for (int t = threadIdx.x; t < 150 * 40; t += 256) {
    int k = t / 40, c = t - k * 40;
    if (jh * 80 + 2 * c < 150) {
      float2 v = *(const float2*)(src + (size_t)k * 150 + 2 * c);
      *(float2*)&lds[k * 82 + 2 * c] = v;
    }
  }
  __syncthreads();
  u16* dst = WtT + (size_t)tri * 15360000 + (size_t)oi * 25600 +
             (size_t)jh * 80 * 160;
  for (int t = threadIdx.x; t < 80 * 20; t += 256) {
    int jl = t / 20, kc = t - jl * 20;
    int j = jh * 80 + jl;
    bool jlive = (j < 150);
    us8 v;
#pragma unroll
    for (int u = 0; u < 8; ++u) {
      int k = kc * 8 + u;
      float f = (jlive && k < 150) ? lds[k * 82 + jl] : 0.f;
      v[u] = f2bf(f);
    }
    *(us8*)(dst + (size_t)jl * 160 + kc * 8) = v;
  }
}

// ---------------------------------------------------------------------------
// Swapped-operand direct-streaming NT-GEMM (no LDS, no barriers).
// M-op rows map to the OUTPUT INNER dim -> packed ushort4 stores.
// STAGE 0: proj. grid (8 nt over 640 j, 2 over 288 rows).
// STAGE 1: grid (2 nt over 160 j, 1200 oi'=tri*600+oi, 2 b).
//   C=wbuf[tri][b][z][o][i][j].
// STAGE 2: grid (2 nt over 160 i, 1152 f2'=tri*576+z*4+o, 2 b).
//   C=tbuf[tri][b][z][o][y][i].
// ---------------------------------------------------------------------------
template <int STAGE>
__global__ __launch_bounds__(192) void gemm_sw(
    const u16* __restrict__ M0, const u16* __restrict__ N0,
    u16* __restrict__ C, const float* __restrict__ bias0,
    const float* __restrict__ bias1, const float* __restrict__ bias2,
    const float* __restrict__ bias3) {
  constexpr int KS = (STAGE == 0) ? 32 : 5;
  constexpr int SR = (STAGE == 0) ? 1024 : 160;
  const u16* Mb;
  const u16* Nb;
  u16* Cb = nullptr;
  if (STAGE == 0) {
    Mb = M0 + (size_t)blockIdx.x * 80 * 1024;
    Nb = N0 + (size_t)blockIdx.y * 144 * 1024;
  } else if (STAGE == 1) {
    int nt = blockIdx.x, oip = blockIdx.y, b = blockIdx.z;
    int tri = (oip >= 600) ? 1 : 0;
    int oi = oip - tri * 600;
    int o = oi / 150, i = oi - o * 150;
    Mb = M0 + (size_t)oip * 25600 + nt * 12800;
    Nb = N0 + (size_t)b * 23040;
    Cb = C + (size_t)tri * 29491200 + (size_t)b * 14745600 +
         ((size_t)o * 160 + i) * 160 + nt * 80;
  } else {
    int nt = blockIdx.x, f2p = blockIdx.y, b = blockIdx.z;
    int tri = (f2p >= 576) ? 1 : 0;
    int f2 = f2p - tri * 576;
    int z = f2 >> 2, o = f2 & 3;
    Mb = M0 + (size_t)tri * 29491200 + (size_t)b * 14745600 +
         (size_t)z * 102400 + o * 25600 + nt * 12800;
    Nb = N0 + (size_t)(tri ? 46080 : 92160) + (size_t)b * 23040;
    Cb = C + (size_t)tri * 26542080 + (size_t)b * 13271040 +
         (size_t)z * 92160 + o * 23040 + nt * 80;
  }
  int tid = threadIdx.x;
  int lane = tid & 63, wave = tid >> 6;
  int l16 = lane & 15, quad = lane >> 4;
  const u16* Mp = Mb + (size_t)l16 * SR + quad * 8;
  const u16* Np = Nb + (size_t)(wave * 48 + l16) * SR + quad * 8;
  f32x4 acc[5][3];
#pragma unroll
  for (int mi = 0; mi < 5; ++mi)
#pragma unroll
    for (int ni = 0; ni < 3; ++ni) acc[mi][ni] = (f32x4){0.f, 0.f, 0.f, 0.f};

#pragma unroll
  for (int ks = 0; ks < KS; ++ks) {
    bf16x8 mf[5], nf[3];
#pragma unroll
    for (int mi = 0; mi < 5; ++mi)
      mf[mi] = *(const bf16x8*)(Mp + (size_t)mi * 16 * SR + ks * 32);
#pragma unroll
    for (int ni = 0; ni < 3; ++ni)
      nf[ni] = *(const bf16x8*)(Np + (size_t)ni * 16 * SR + ks * 32);
#pragma unroll
    for (int mi = 0; mi < 5; ++mi)
#pragma unroll
      for (int ni = 0; ni < 3; ++ni)
        acc[mi][ni] = __builtin_amdgcn_mfma_f32_16x16x32_bf16(
            mf[mi], nf[ni], acc[mi][ni], 0, 0, 0);
  }

  if (STAGE == 0) {
    int p = blockIdx.x >> 1;
    const float* bp =
        (p == 0) ? bias0 : (p == 1) ? bias1 : (p == 2) ? bias2 : bias3;
    int jb0 = (blockIdx.x & 1) * 80;
#pragma unroll
    for (int mi = 0; mi < 5; ++mi) {
      int jb = jb0 + mi * 16 + quad * 4;
#pragma unroll
      for (int ni = 0; ni < 3; ++ni) {
        int row = blockIdx.y * 144 + wave * 48 + ni * 16 + l16;
        ushort4 pk;
        float v0 = (jb + 0 < 150) ? acc[mi][ni][0] + bp[jb + 0] : 0.f;
        float v1 = (jb + 1 < 150) ? acc[mi][ni][1] + bp[jb + 1] : 0.f;
        float v2 = (jb + 2 < 150) ? acc[mi][ni][2] + bp[jb + 2] : 0.f;
        float v3 = (jb + 3 < 150) ? acc[mi][ni][3] + bp[jb + 3] : 0.f;
        pk.x = f2bf(v0); pk.y = f2bf(v1); pk.z = f2bf(v2); pk.w = f2bf(v3);
        *(ushort4*)(C + ((size_t)p * 288 + row) * 160 + jb) = pk;
      }
    }
  } else {
#pragma unroll
    for (int mi = 0; mi < 5; ++mi) {
      int mb4 = mi * 16 + quad * 4;
#pragma unroll
      for (int ni = 0; ni < 3; ++ni) {
        int outer = wave * 48 + ni * 16 + l16;
        ushort4 pk;
        pk.x = f2bf(acc[mi][ni][0]); pk.y = f2bf(acc[mi][ni][1]);
        pk.z = f2bf(acc[mi][ni][2]); pk.w = f2bf(acc[mi][ni][3]);
        size_t off = (STAGE == 1) ? ((size_t)outer * 102400 + mb4)
                                  : ((size_t)outer * 160 + mb4);
        *(ushort4*)(Cb + off) = pk;
      }
    }
  }
}

// ---------------------------------------------------------------------------
// stage3 + mask + log_softmax, o-in-register variant. Block 256 = 4 waves.
// NO LDS, no barriers. A-operand rows interleave o into the low 2 bits of M:
// m = row*4 + o  (per-lane addr: o = l16&3, row = l16>>2). After MFMA each
// lane's f32x4 (r=0..3) holds the 4 o-values of one (x,y) cell -> in-register
// log_softmax -> one float4 store to o-contiguous output.
// Waves split the A-row dim (y for VAR0, x for VAR1) in 12-row chunks.
// grid (6 = xtile*2+b, 3 ytile, 144 z).
// VAR0: out[x][y][o] = lsm_o( sum_i st[x,i] * t1[z,o][y][i] )
// VAR1: out[x][y][o] = lsm_o( sum_i t2[z,o][x][i] * ot[y,i] )
// ---------------------------------------------------------------------------
template <int VAR>
__global__ __launch_bounds__(256) void stage3_kernel(
    const u16* __restrict__ tb, const u16* __restrict__ P,
    float* __restrict__ out, int BT) {
  int bx = blockIdx.x;
  int b = bx & 1, xt = (bx >> 1) * 48;
  int yt = blockIdx.y * 48;
  int zg = blockIdx.z;
  int tid = threadIdx.x;
  const float NL4 = -1.3862943611198906f;
  size_t obase = ((size_t)(b * 144 + zg)) * 82944;
  if (zg > xt + 47) {  // fully masked tile
    float4 v = make_float4(NL4, NL4, NL4, NL4);
    for (int p = tid; p < 2304; p += 256) {
      int xl = p / 48, yl = p - xl * 48;
      *(float4*)(out + obase + ((size_t)(xt + xl) * 144 + yt + yl) * 4) = v;
    }
    return;
  }
  int lane = tid & 63, wave = tid >> 6, l16 = lane & 15, quad = lane >> 4;
  int o = l16 & 3, rq = l16 >> 2;
  int arow0 = (VAR == 0) ? yt : xt;  // T-row dim: y (VAR0) / x (VAR1)
  int nrow0 = (VAR == 0) ? xt : yt;  // N dim: st x rows / ot y rows
  const u16* Ap = tb + (size_t)b * BT + (size_t)zg * 92160 +
                  (size_t)o * 23040 +
                  (size_t)(arow0 + wave * 12 + rq) * 160 + quad * 8;
  const u16* Bp =
      P + (size_t)b * 23040 + (size_t)(nrow0 + l16) * 160 + quad * 8;
  f32x4 acc[3][3];
#pragma unroll
  for (int mi = 0; mi < 3; ++mi)
#pragma unroll
    for (int ni = 0; ni < 3; ++ni) acc[mi][ni] = (f32x4){0.f, 0.f, 0.f, 0.f};

#pragma unroll
  for (int ks = 0; ks < 5; ++ks) {
    bf16x8 af[3], bfr[3];
#pragma unroll
    for (int mi = 0; mi < 3; ++mi)
      af[mi] = *(const bf16x8*)(Ap + (size_t)mi * 4 * 160 + ks * 32);
#pragma unroll
    for (int ni = 0; ni < 3; ++ni)
      bfr[ni] = *(const bf16x8*)(Bp + (size_t)ni * 16 * 160 + ks * 32);
#pragma unroll
    for (int mi = 0; mi < 3; ++mi)
#pragma unroll
      for (int ni = 0; ni < 3; ++ni)
        acc[mi][ni] = __builtin_amdgcn_mfma_f32_16x16x32_bf16(
            af[mi], bfr[ni], acc[mi][ni], 0, 0, 0);
  }

#pragma unroll
  for (int mi = 0; mi < 3; ++mi) {
    int arow = arow0 + wave * 12 + mi * 4 + quad;
#pragma unroll
    for (int ni = 0; ni < 3; ++ni) {
      int nrow = nrow0 + ni * 16 + l16;
      int xg = (VAR == 0) ? nrow : arow;
      int yg = (VAR == 0) ? arow : nrow;
      float4 v;
      if (zg > xg) {
        v = make_float4(NL4, NL4, NL4, NL4);
      } else {
        float c0 = acc[mi][ni][0], c1 = acc[mi][ni][1];
        float c2 = acc[mi][ni][2], c3 = acc[mi][ni][3];
        float mx = fmaxf(fmaxf(c0, c1), fmaxf(c2, c3));
        float l = mx + logf(expf(c0 - mx) + expf(c1 - mx) + expf(c2 - mx) +
                            expf(c3 - mx));
        v = make_float4(c0 - l, c1 - l, c2 - l, c3 - l);
      }
      *(float4*)(out + obase + ((size_t)xg * 144 + yg) * 4) = v;
    }
  }
}

// ---------------------------------------------------------------------------
extern "C" void kernel_launch(void* const* d_in, const int* in_sizes, int n_in,
                              void* d_out, int out_size, void* d_ws,
                              size_t ws_size, hipStream_t stream) {
  const float* x = (const float*)d_in[0];
  const float* Wsh = (const float*)d_in[1];
  const float* bsh = (const float*)d_in[2];
  const float* Wst = (const float*)d_in[3];
  const float* bst = (const float*)d_in[4];
  const float* Woh = (const float*)d_in[5];
  const float* boh = (const float*)d_in[6];
  const float* Wot = (const float*)d_in[7];
  const float* bot = (const float*)d_in[8];
  const float* Wt1 = (const float*)d_in[9];
  const float* Wt2 = (const float*)d_in[10];

  u16* ws = (u16*)d_ws;
  u16* xb = ws;                    // 294912
  u16* WT4 = ws + 294912;          // 655360
  u16* pAll = ws + 950272;         // 184320 : [p][288][160]
  u16* WtT = ws + 1134592;         // 2 x 15360000 : [tri][600][160][160]
  u16* wbuf = ws + 31854592;       // 58982400 : [tri][b][144][4][160][160]
  u16* tbuf = ws + 90836992;       // 53084160 : [tri][b][144][4][144][160]
  (void)ws_size;

  conv_x<<<288, 256, 0, stream>>>(x, xb);
  trans_wp<<<dim3(16, 4), 256, 0, stream>>>(Wsh, Wst, Woh, Wot, WT4);
  transw2<<<dim3(600, 2, 2), 256, 0, stream>>>(Wt1, Wt2, WtT);
  gemm_sw<0><<<dim3(8, 2), 192, 0, stream>>>(WT4, xb, pAll, bsh, bst, boh,
                                             bot);
  gemm_sw<1><<<dim3(2, 1200, 2), 192, 0, stream>>>(WtT, pAll, wbuf, nullptr,
                                                   nullptr, nullptr, nullptr);
  gemm_sw<2><<<dim3(2, 1152, 2), 192, 0, stream>>>(wbuf, pAll, tbuf, nullptr,
                                                   nullptr, nullptr, nullptr);

  float* out0 = (float*)d_out;
  float* out1 = out0 + 23887872;  // 2*144^3*4
  stage3_kernel<0><<<dim3(6, 3, 144), 256, 0, stream>>>(
      tbuf, pAll + 46080, out0, 13271040);
  stage3_kernel<1><<<dim3(6, 3, 144), 256, 0, stream>>>(
      tbuf + 26542080, pAll + 138240, out1, 13271040);
}

// Round 4
// 610.823 us; speedup vs baseline: 1.0339x; 1.0339x over previous
//
#include <hip/hip_runtime.h>
#include <hip/hip_bf16.h>
#include <math.h>

typedef unsigned short u16;
typedef __attribute__((ext_vector_type(8))) short bf16x8;
typedef __attribute__((ext_vector_type(8))) unsigned short us8;
typedef __attribute__((ext_vector_type(4))) float f32x4;

static __device__ __forceinline__ u16 f2bf(float f) {
  __hip_bfloat16 h = __float2bfloat16(f);
  return *reinterpret_cast<u16*>(&h);
}

// ---------------------------------------------------------------------------
// K0: x fp32 -> bf16 (288x1024)
// ---------------------------------------------------------------------------
__global__ __launch_bounds__(256) void conv_x(const float* __restrict__ x,
                                              u16* __restrict__ xb) {
  int idx = (blockIdx.x * 256 + threadIdx.x) * 4;
  float4 v = *(const float4*)(x + idx);
  ushort4 o;
  o.x = f2bf(v.x); o.y = f2bf(v.y); o.z = f2bf(v.z); o.w = f2bf(v.w);
  *(ushort4*)(xb + idx) = o;
}

// ---------------------------------------------------------------------------
// K0b: W_proj [1024][150] fp32 -> WT4 [p][160][1024] bf16, pads (j>=150) zero
// ---------------------------------------------------------------------------
__global__ __launch_bounds__(256) void trans_wp(
    const float* __restrict__ W0, const float* __restrict__ W1,
    const float* __restrict__ W2, const float* __restrict__ W3,
    u16* __restrict__ WT4) {
  __shared__ float lds[64 * 151];
  int kt = blockIdx.x, p = blockIdx.y;
  const float* W = (p == 0) ? W0 : (p == 1) ? W1 : (p == 2) ? W2 : W3;
  for (int t = threadIdx.x; t < 64 * 150; t += 256) {
    int k = t / 150, j = t - k * 150;
    lds[k * 151 + j] = W[(size_t)(kt * 64 + k) * 150 + j];
  }
  __syncthreads();
  u16* dst = WT4 + (size_t)p * 160 * 1024 + kt * 64;
  for (int t = threadIdx.x; t < 160 * 64; t += 256) {
    int j = t >> 6, kk = t & 63;
    float v = (j < 150) ? lds[kk * 151 + j] : 0.f;
    dst[(size_t)j * 1024 + kk] = f2bf(v);
  }
}

// ---------------------------------------------------------------------------
// transpose W_tri [600 oi][150 k][150 j] fp32 -> WtT [tri][600][160 j][160 k]
// bf16. grid (600, 2 jhalf, 2 tri). LDS 49.2 KB -> 3 blocks/CU.
// ---------------------------------------------------------------------------
__global__ __launch_bounds__(256) void transw2(const float* __restrict__ Wa,
                                               const float* __restrict__ Wb,
                                               u16* __restrict__ WtT) {
  __shared__ float lds[150 * 82];
  int oi = blockIdx.x, jh = blockIdx.y, tri = blockIdx.z;
  const float* W = tri ? Wb : Wa;
  const float* src = W + (size_t)oi * 22500 + jh * 80;
  for (int t = threadIdx.x; t < 150 * 40; t += 256) {
    int k = t / 40, c = t - k * 40;
    if (jh * 80 + 2 * c < 150) {
      float2 v = *(const float2*)(src + (size_t)k * 150 + 2 * c);
      *(float2*)&lds[k * 82 + 2 * c] = v;
    }
  }
  __syncthreads();
  u16* dst = WtT + (size_t)tri * 15360000 + (size_t)oi * 25600 +
             (size_t)jh * 80 * 160;
  for (int t = threadIdx.x; t < 80 * 20; t += 256) {
    int jl = t / 20, kc = t - jl * 20;
    int j = jh * 80 + jl;
    bool jlive = (j < 150);
    us8 v;
#pragma unroll
    for (int u = 0; u < 8; ++u) {
      int k = kc * 8 + u;
      float f = (jlive && k < 150) ? lds[k * 82 + jl] : 0.f;
      v[u] = f2bf(f);
    }
    *(us8*)(dst + (size_t)jl * 160 + kc * 8) = v;
  }
}

// ---------------------------------------------------------------------------
// Swapped-operand direct-streaming NT-GEMM (no LDS, no barriers).
// STAGE 0: proj. grid (8 nt over 640 j, 2 over 288 rows).
// STAGE 1: grid (2 nt over 160 j, 1200 oi'=tri*600+oi, 2 b).
//   C=wbuf[tri][b][z][o][i][j] (z stride 102400).
// ---------------------------------------------------------------------------
template <int STAGE>
__global__ __launch_bounds__(192) void gemm_sw(
    const u16* __restrict__ M0, const u16* __restrict__ N0,
    u16* __restrict__ C, const float* __restrict__ bias0,
    const float* __restrict__ bias1, const float* __restrict__ bias2,
    const float* __restrict__ bias3) {
  constexpr int KS = (STAGE == 0) ? 32 : 5;
  constexpr int SR = (STAGE == 0) ? 1024 : 160;
  const u16* Mb;
  const u16* Nb;
  u16* Cb = nullptr;
  if (STAGE == 0) {
    Mb = M0 + (size_t)blockIdx.x * 80 * 1024;
    Nb = N0 + (size_t)blockIdx.y * 144 * 1024;
  } else {
    int nt = blockIdx.x, oip = blockIdx.y, b = blockIdx.z;
    int tri = (oip >= 600) ? 1 : 0;
    int oi = oip - tri * 600;
    int o = oi / 150, i = oi - o * 150;
    Mb = M0 + (size_t)oip * 25600 + nt * 12800;
    Nb = N0 + (size_t)b * 23040;
    Cb = C + (size_t)tri * 29491200 + (size_t)b * 14745600 +
         ((size_t)o * 160 + i) * 160 + nt * 80;
  }
  int tid = threadIdx.x;
  int lane = tid & 63, wave = tid >> 6;
  int l16 = lane & 15, quad = lane >> 4;
  const u16* Mp = Mb + (size_t)l16 * SR + quad * 8;
  const u16* Np = Nb + (size_t)(wave * 48 + l16) * SR + quad * 8;
  f32x4 acc[5][3];
#pragma unroll
  for (int mi = 0; mi < 5; ++mi)
#pragma unroll
    for (int ni = 0; ni < 3; ++ni) acc[mi][ni] = (f32x4){0.f, 0.f, 0.f, 0.f};

#pragma unroll
  for (int ks = 0; ks < KS; ++ks) {
    bf16x8 mf[5], nf[3];
#pragma unroll
    for (int mi = 0; mi < 5; ++mi)
      mf[mi] = *(const bf16x8*)(Mp + (size_t)mi * 16 * SR + ks * 32);
#pragma unroll
    for (int ni = 0; ni < 3; ++ni)
      nf[ni] = *(const bf16x8*)(Np + (size_t)ni * 16 * SR + ks * 32);
#pragma unroll
    for (int mi = 0; mi < 5; ++mi)
#pragma unroll
      for (int ni = 0; ni < 3; ++ni)
        acc[mi][ni] = __builtin_amdgcn_mfma_f32_16x16x32_bf16(
            mf[mi], nf[ni], acc[mi][ni], 0, 0, 0);
  }

  if (STAGE == 0) {
    int p = blockIdx.x >> 1;
    const float* bp =
        (p == 0) ? bias0 : (p == 1) ? bias1 : (p == 2) ? bias2 : bias3;
    int jb0 = (blockIdx.x & 1) * 80;
#pragma unroll
    for (int mi = 0; mi < 5; ++mi) {
      int jb = jb0 + mi * 16 + quad * 4;
#pragma unroll
      for (int ni = 0; ni < 3; ++ni) {
        int row = blockIdx.y * 144 + wave * 48 + ni * 16 + l16;
        ushort4 pk;
        float v0 = (jb + 0 < 150) ? acc[mi][ni][0] + bp[jb + 0] : 0.f;
        float v1 = (jb + 1 < 150) ? acc[mi][ni][1] + bp[jb + 1] : 0.f;
        float v2 = (jb + 2 < 150) ? acc[mi][ni][2] + bp[jb + 2] : 0.f;
        float v3 = (jb + 3 < 150) ? acc[mi][ni][3] + bp[jb + 3] : 0.f;
        pk.x = f2bf(v0); pk.y = f2bf(v1); pk.z = f2bf(v2); pk.w = f2bf(v3);
        *(ushort4*)(C + ((size_t)p * 288 + row) * 160 + jb) = pk;
      }
    }
  } else {
#pragma unroll
    for (int mi = 0; mi < 5; ++mi) {
      int mb4 = mi * 16 + quad * 4;
#pragma unroll
      for (int ni = 0; ni < 3; ++ni) {
        int outer = wave * 48 + ni * 16 + l16;
        ushort4 pk;
        pk.x = f2bf(acc[mi][ni][0]); pk.y = f2bf(acc[mi][ni][1]);
        pk.z = f2bf(acc[mi][ni][2]); pk.w = f2bf(acc[mi][ni][3]);
        *(ushort4*)(Cb + (size_t)outer * 102400 + mb4) = pk;
      }
    }
  }
}

// ---------------------------------------------------------------------------
// fuse23: stage2 + stage3 + mask + log_softmax in one kernel (tbuf removed).
// grid (3 seg, 144 z, 2 b), 256 thr = 4 waves.
// Phase A (old gemm2): wave o computes t[(local,o)][i] = sum_j w[z,o,i,j] *
//   Pn[segbase+local, j]  (Pn = oh for VAR0 / st for VAR1), M=i(10 frags),
//   N=local(3 frags), K=j(160). Result rows i are quad*4+r-contiguous ->
//   ushort4 into LDS row m=local*4+o, stride 168 u16 (336B = 21*16B, odd
//   group stride -> near-conflict-free b128 reads in phase B).
// Phase B (old stage3, o-in-register): for each 16-wide n-tile (x for VAR0 /
//   y for VAR1), mfma(A=t rows m, B=P2 rows n): lane holds the 4 o-values of
//   one (x,y) cell -> in-register log_softmax -> float4 store.
//   VAR0: masked x-tiles (xt+15 < z) fast-fill NL4. VAR1: fully-masked
//   x-blocks (seg*48+47 < z) skip everything and fill.
// ---------------------------------------------------------------------------
template <int VAR>
__global__ __launch_bounds__(256) void fuse23(const u16* __restrict__ wb,
                                              const u16* __restrict__ pA,
                                              float* __restrict__ out) {
  constexpr int TSTR = 168;
  __shared__ __align__(16) u16 t_lds[192 * TSTR];  // 64.5 KB
  int seg = blockIdx.x, zg = blockIdx.y, b = blockIdx.z;
  int tid = threadIdx.x, lane = tid & 63, wave = tid >> 6;
  int l16 = lane & 15, quad = lane >> 4;
  const float NL4 = -1.3862943611198906f;
  size_t obase = ((size_t)(b * 144 + zg)) * 82944;

  if (VAR == 1 && seg * 48 + 47 < zg) {  // whole x-block masked
    float4 v = make_float4(NL4, NL4, NL4, NL4);
    for (int p = tid; p < 48 * 144; p += 256) {
      int xl = p / 144, y = p - xl * 144;
      *(float4*)(out + obase + ((size_t)(seg * 48 + xl) * 144 + y) * 4) = v;
    }
    return;
  }

  // ---- Phase A ----
  {
    const u16* wsl = wb + (size_t)b * 14745600 + (size_t)zg * 102400 +
                     (size_t)wave * 25600 + (size_t)l16 * 160 + quad * 8;
    const u16* np = pA + (size_t)(VAR ? 1 : 2) * 46080 + (size_t)b * 23040 +
                    (size_t)(seg * 48 + l16) * 160 + quad * 8;
    f32x4 aa[10][3];
#pragma unroll
    for (int mi = 0; mi < 10; ++mi)
#pragma unroll
      for (int ni = 0; ni < 3; ++ni) aa[mi][ni] = (f32x4){0.f, 0.f, 0.f, 0.f};
#pragma unroll
    for (int ks = 0; ks < 5; ++ks) {
      bf16x8 mf[10], nf[3];
#pragma unroll
      for (int mi = 0; mi < 10; ++mi)
        mf[mi] = *(const bf16x8*)(wsl + mi * 2560 + ks * 32);
#pragma unroll
      for (int ni = 0; ni < 3; ++ni)
        nf[ni] = *(const bf16x8*)(np + (size_t)ni * 16 * 160 + ks * 32);
#pragma unroll
      for (int mi = 0; mi < 10; ++mi)
#pragma unroll
        for (int ni = 0; ni < 3; ++ni)
          aa[mi][ni] = __builtin_amdgcn_mfma_f32_16x16x32_bf16(
              mf[mi], nf[ni], aa[mi][ni], 0, 0, 0);
    }
#pragma unroll
    for (int mi = 0; mi < 10; ++mi)
#pragma unroll
      for (int ni = 0; ni < 3; ++ni) {
        int row = (ni * 16 + l16) * 4 + wave;  // m = local*4 + o
        int ib = mi * 16 + quad * 4;
        ushort4 pk;
        pk.x = f2bf(aa[mi][ni][0]); pk.y = f2bf(aa[mi][ni][1]);
        pk.z = f2bf(aa[mi][ni][2]); pk.w = f2bf(aa[mi][ni][3]);
        *(ushort4*)&t_lds[row * TSTR + ib] = pk;
      }
  }
  __syncthreads();

  // ---- Phase B ----
  const u16* pn2 = pA + (size_t)(VAR ? 3 : 1) * 46080 + (size_t)b * 23040;
  int nt[3];
  bool lv[3];
  const u16* np2[3];
#pragma unroll
  for (int t = 0; t < 3; ++t) {
    nt[t] = wave + t * 4;
    lv[t] = (nt[t] < 9) && (VAR == 1 || nt[t] * 16 + 15 >= zg);
    int ntc = (nt[t] < 9) ? nt[t] : 0;
    np2[t] = pn2 + (size_t)(ntc * 16 + l16) * 160 + quad * 8;
  }
  f32x4 ac[12][3];
#pragma unroll
  for (int mi = 0; mi < 12; ++mi)
#pragma unroll
    for (int t = 0; t < 3; ++t) ac[mi][t] = (f32x4){0.f, 0.f, 0.f, 0.f};

#pragma unroll
  for (int ks = 0; ks < 5; ++ks) {
    bf16x8 nf0 = *(const bf16x8*)(np2[0] + ks * 32);
    bf16x8 nf1 = *(const bf16x8*)(np2[1] + ks * 32);
    bf16x8 nf2 = *(const bf16x8*)(np2[2] + ks * 32);
#pragma unroll
    for (int mi = 0; mi < 12; ++mi) {
      bf16x8 af =
          *(const bf16x8*)&t_lds[(mi * 16 + l16) * TSTR + ks * 32 + quad * 8];
      if (lv[0])
        ac[mi][0] =
            __builtin_amdgcn_mfma_f32_16x16x32_bf16(af, nf0, ac[mi][0], 0, 0, 0);
      if (lv[1])
        ac[mi][1] =
            __builtin_amdgcn_mfma_f32_16x16x32_bf16(af, nf1, ac[mi][1], 0, 0, 0);
      if (lv[2])
        ac[mi][2] =
            __builtin_amdgcn_mfma_f32_16x16x32_bf16(af, nf2, ac[mi][2], 0, 0, 0);
    }
  }

#pragma unroll
  for (int t = 0; t < 3; ++t) {
    if (nt[t] >= 9) continue;
    int nb = nt[t] * 16 + l16;
    if (lv[t]) {
#pragma unroll
      for (int mi = 0; mi < 12; ++mi) {
        int loc = seg * 48 + mi * 4 + quad;
        int xg = (VAR == 0) ? nb : loc;
        int yg = (VAR == 0) ? loc : nb;
        float4 v;
        if (zg > xg) {
          v = make_float4(NL4, NL4, NL4, NL4);
        } else {
          float c0 = ac[mi][t][0], c1 = ac[mi][t][1];
          float c2 = ac[mi][t][2], c3 = ac[mi][t][3];
          float mx = fmaxf(fmaxf(c0, c1), fmaxf(c2, c3));
          float l = mx + logf(expf(c0 - mx) + expf(c1 - mx) + expf(c2 - mx) +
                              expf(c3 - mx));
          v = make_float4(c0 - l, c1 - l, c2 - l, c3 - l);
        }
        *(float4*)(out + obase + ((size_t)xg * 144 + yg) * 4) = v;
      }
    } else {  // VAR0 masked x-tile: fill NL4
      float4 v = make_float4(NL4, NL4, NL4, NL4);
#pragma unroll
      for (int mi = 0; mi < 12; ++mi) {
        int y = seg * 48 + mi * 4 + quad;
        *(float4*)(out + obase + ((size_t)nb * 144 + y) * 4) = v;
      }
    }
  }
}

// ---------------------------------------------------------------------------
extern "C" void kernel_launch(void* const* d_in, const int* in_sizes, int n_in,
                              void* d_out, int out_size, void* d_ws,
                              size_t ws_size, hipStream_t stream) {
  const float* x = (const float*)d_in[0];
  const float* Wsh = (const float*)d_in[1];
  const float* bsh = (const float*)d_in[2];
  const float* Wst = (const float*)d_in[3];
  const float* bst = (const float*)d_in[4];
  const float* Woh = (const float*)d_in[5];
  const float* boh = (const float*)d_in[6];
  const float* Wot = (const float*)d_in[7];
  const float* bot = (const float*)d_in[8];
  const float* Wt1 = (const float*)d_in[9];
  const float* Wt2 = (const float*)d_in[10];

  u16* ws = (u16*)d_ws;
  u16* xb = ws;                    // 294912
  u16* WT4 = ws + 294912;          // 655360
  u16* pAll = ws + 950272;         // 184320 : [p][288][160]
  u16* WtT = ws + 1134592;         // 2 x 15360000 : [tri][600][160][160]
  u16* wbuf = ws + 31854592;       // 58982400 : [tri][b][144][4][160][160]
  (void)ws_size;

  conv_x<<<288, 256, 0, stream>>>(x, xb);
  trans_wp<<<dim3(16, 4), 256, 0, stream>>>(Wsh, Wst, Woh, Wot, WT4);
  transw2<<<dim3(600, 2, 2), 256, 0, stream>>>(Wt1, Wt2, WtT);
  gemm_sw<0><<<dim3(8, 2), 192, 0, stream>>>(WT4, xb, pAll, bsh, bst, boh,
                                             bot);
  gemm_sw<1><<<dim3(2, 1200, 2), 192, 0, stream>>>(WtT, pAll, wbuf, nullptr,
                                                   nullptr, nullptr, nullptr);

  float* out0 = (float*)d_out;
  float* out1 = out0 + 23887872;  // 2*144^3*4
  fuse23<0><<<dim3(3, 144, 2), 256, 0, stream>>>(wbuf, pAll, out0);
  fuse23<1><<<dim3(3, 144, 2), 256, 0, stream>>>(wbuf + 29491200, pAll, out1);
}